// Round 6
// baseline (21.080 us; speedup 1.0000x reference)
//
#include <hip/hip_runtime.h>
#include <hip/hip_bf16.h>
#include <float.h>

// MeshLoss: out = mean_b,m( min_n |pc[b,m]-top[b,n]|^2 ) + mean((bottom-fem_bottom)^2)
// network_mesh (4,3,32,16,32) f32, pc (4,3,16384) f32, fem_mesh (4,3,32,16,32) f32.
// top[b,n] = network_mesh[b,:, n>>5, 15, n&31], n in [0,1024)
//
// |p-t|^2 = |p|^2 + (|t|^2 - 2 p.t): stage (tx,ty,tz,|t|^2) in LDS; per pair
// d' = fma(-2px,tx, fma(-2py,ty, fma(-2pz,tz, t2))) = 3 FMA, pairs folded via
// v_min3_f32 -> 3.5 VALU/pair. |p|^2 added at the tile-partial write.
//
// R5 post-mortem: at 2 waves/SIMD the K1 loop (4 ds_read -> wait -> compute)
// is LDS-LATENCY-bound, not throughput-bound. This round: 4 waves/SIMD
// (1024 blocks = 4 blocks/CU, __launch_bounds__(256,4)) and 8 outstanding
// ds_read_b128 per inner iteration so the ~100cy LDS latency is fully hidden.
//
// K1: 1024 blocks x 256 thr = 4 batches x 8 pc-chunks(2048, P=8/thread)
//     x 32 top-tiles(32 tops). Tile partial mins (+|p|^2) -> ws[tile][65536]
//     (8 MB). Block 0 zeroes out[0] (K2 strictly after K1).
// K2: 256 blocks x 256 thr: per thread one point: 32-way tile min (L2-resident,
//     32 independent coalesced loads), fem MSE (threads < 46080), block-reduce,
//     one atomicAdd per block into out[0].

#define B_BATCH         4
#define MPTS            16384
#define NM_BATCH_STRIDE 49152     // 3*32*16*32 (== pc batch stride)
#define CH_STRIDE       16384

#define PC_PER_THREAD   8
#define PC_CHUNK        2048      // 256 threads * 8
#define N_CHUNKS        8
#define N_TILES         32
#define TILE_TOPS       32        // 1024 / 32

#define NUM_DIST_BLOCKS (B_BATCH * N_CHUNKS * N_TILES)   // 1024
#define NUM_RED_BLOCKS  256

#define TOTAL_M         65536     // B*M
#define FEM_VEC4        46080     // 184320/4

__device__ __forceinline__ float block_reduce_sum(float v) {
    for (int o = 32; o > 0; o >>= 1) v += __shfl_down(v, o, 64);
    __shared__ float s[4];
    int lane = threadIdx.x & 63;
    int w    = threadIdx.x >> 6;
    if (lane == 0) s[w] = v;
    __syncthreads();
    if (threadIdx.x == 0) v = s[0] + s[1] + s[2] + s[3];
    return v;
}

__global__ __launch_bounds__(256, 4) void meshloss_dist(
    const float* __restrict__ nm,
    const float* __restrict__ pc,
    float* __restrict__ ws,
    float* __restrict__ out)
{
    const int t   = threadIdx.x;
    const int bid = blockIdx.x;

    if (bid == 0 && t == 0) out[0] = 0.0f;   // K2 runs after K1: no race

    const int b     = bid >> 8;          // /256: batch
    const int rem   = bid & 255;
    const int chunk = rem >> 5;          // 8 pc chunks of 2048
    const int tile  = rem & 31;          // 32 top tiles of 32

    __shared__ float4 top[TILE_TOPS];    // 512 B
    const float* nmb = nm + b * NM_BATCH_STRIDE;
    if (t < TILE_TOPS) {
        const int p = tile * TILE_TOPS + t;
        const int i = p >> 5, k = p & 31;
        const int base = i * 512 + 480 + k;     // (i*16+15)*32 + k
        float x = nmb[0 * CH_STRIDE + base];
        float y = nmb[1 * CH_STRIDE + base];
        float z = nmb[2 * CH_STRIDE + base];
        top[t] = make_float4(x, y, z, x * x + y * y + z * z);
    }
    __syncthreads();

    const float* pcb = pc + b * NM_BATCH_STRIDE;
    const int mbase = chunk * PC_CHUNK + t;

    float px2[PC_PER_THREAD], py2[PC_PER_THREAD], pz2[PC_PER_THREAD];
    float pp[PC_PER_THREAD], mn[PC_PER_THREAD];
    #pragma unroll
    for (int j = 0; j < PC_PER_THREAD; ++j) {
        const int m = mbase + j * 256;
        float x = pcb[m];
        float y = pcb[CH_STRIDE + m];
        float z = pcb[2 * CH_STRIDE + m];
        pp[j]  = x * x + y * y + z * z;
        px2[j] = -2.0f * x;
        py2[j] = -2.0f * y;
        pz2[j] = -2.0f * z;
        mn[j]  = FLT_MAX;
    }

    // 4 groups of 8 tops: 8 outstanding ds_read_b128, then 224 VALU insts.
    #pragma unroll
    for (int g = 0; g < TILE_TOPS / 8; ++g) {
        float4 T0 = top[g * 8 + 0];
        float4 T1 = top[g * 8 + 1];
        float4 T2 = top[g * 8 + 2];
        float4 T3 = top[g * 8 + 3];
        float4 T4 = top[g * 8 + 4];
        float4 T5 = top[g * 8 + 5];
        float4 T6 = top[g * 8 + 6];
        float4 T7 = top[g * 8 + 7];
        #pragma unroll
        for (int j = 0; j < PC_PER_THREAD; ++j) {
            #define DISTD(T) __builtin_fmaf(px2[j], T.x, \
                             __builtin_fmaf(py2[j], T.y, \
                             __builtin_fmaf(pz2[j], T.z, T.w)))
            float d0 = DISTD(T0);
            float d1 = DISTD(T1);
            float d2 = DISTD(T2);
            float d3 = DISTD(T3);
            float d4 = DISTD(T4);
            float d5 = DISTD(T5);
            float d6 = DISTD(T6);
            float d7 = DISTD(T7);
            #undef DISTD
            mn[j] = fminf(mn[j], fminf(d0, d1));   // v_min3_f32
            mn[j] = fminf(mn[j], fminf(d2, d3));
            mn[j] = fminf(mn[j], fminf(d4, d5));
            mn[j] = fminf(mn[j], fminf(d6, d7));
        }
    }

    float* wrow = ws + tile * TOTAL_M + b * MPTS;
    #pragma unroll
    for (int j = 0; j < PC_PER_THREAD; ++j)
        wrow[mbase + j * 256] = mn[j] + pp[j];
}

__global__ __launch_bounds__(256) void meshloss_reduce(
    const float* __restrict__ ws,
    const float* __restrict__ nm,
    const float* __restrict__ fem,
    float* __restrict__ out)
{
    const int gid = blockIdx.x * 256 + threadIdx.x;   // 0..65535

    // ---- dist: min over 32 tile partials (independent coalesced loads) ----
    float v = ws[gid];
    #pragma unroll
    for (int tl = 1; tl < N_TILES; ++tl)
        v = fminf(v, ws[tl * TOTAL_M + gid]);
    float acc = v * (1.0f / 65536.0f);

    // ---- fem MSE: one float4 pair for threads < 46080 ----
    if (gid < FEM_VEC4) {
        const int bci = gid / 120;
        const int r   = gid - bci * 120;
        const int s   = bci * 128 + r;
        float4 a = reinterpret_cast<const float4*>(nm)[s];
        float4 f = reinterpret_cast<const float4*>(fem)[s];
        float dx = a.x - f.x, dy = a.y - f.y, dz = a.z - f.z, dw = a.w - f.w;
        acc += (dx * dx + dy * dy + dz * dz + dw * dw) * (1.0f / 184320.0f);
    }

    float s = block_reduce_sum(acc);
    if (threadIdx.x == 0) atomicAdd(out, s);
}

extern "C" void kernel_launch(void* const* d_in, const int* in_sizes, int n_in,
                              void* d_out, int out_size, void* d_ws, size_t ws_size,
                              hipStream_t stream) {
    const float* nm  = (const float*)d_in[0];
    const float* pc  = (const float*)d_in[1];
    const float* fem = (const float*)d_in[2];
    float* out = (float*)d_out;
    float* ws  = (float*)d_ws;

    meshloss_dist<<<NUM_DIST_BLOCKS, 256, 0, stream>>>(nm, pc, ws, out);
    meshloss_reduce<<<NUM_RED_BLOCKS, 256, 0, stream>>>(ws, nm, fem, out);
}

// Round 7
// 14.063 us; speedup vs baseline: 1.4990x; 1.4990x over previous
//
#include <hip/hip_runtime.h>
#include <hip/hip_bf16.h>
#include <float.h>

// MeshLoss: out = mean_b,m( min_n |pc[b,m]-top[b,n]|^2 ) + mean((bottom-fem_bottom)^2)
// network_mesh (4,3,32,16,32) f32, pc (4,3,16384) f32, fem_mesh (4,3,32,16,32) f32.
// top[b,n] = network_mesh[b,:, n>>5, 15, n&31], n in [0,1024)
//
// |p-t|^2 = |p|^2 + (|t|^2 - 2 p.t): tops staged as (x,y,z,|t|^2); per pair
// d' = fma(-2px,tx, fma(-2py,ty, fma(-2pz,tz, t2))) = 3 FMA, folded pairwise
// into v_min3_f32 -> 3.5 VALU/pair.
//
// R6 post-mortem: regression tracked ws size + same-address atomic count, not
// K1. This round eliminates BOTH: single fused kernel, no dist ws round-trip,
// no atomics.
//
// K1: 256 blocks x 512 thr (1 block/CU, 2 waves/SIMD). Block = (batch, 256-pt
//     chunk). All 1024 tops staged once in LDS (16 KB); the 8 waves PARTITION
//     the tops (128 each) and each wave covers all 256 block points (4/lane).
//     -> each top read from LDS exactly once per block: 1024 b128-reads/CU
//     (~12.3K cyc, the binding pipe; VALU 7.2K cyc/SIMD underneath).
//     Per-wave mins (+|p|^2) -> pm[8][256] in LDS -> 8-way min by threads
//     t<256; fem MSE slice (180 float4 pairs/block) folded in; block sum
//     stored to ws[block] (plain store).
// K2: 1 block x 256 thr: fixed-order sum of the 256 partials -> out[0].

#define B_BATCH         4
#define NM_BATCH_STRIDE 49152     // 3*32*16*32 (== pc batch stride)
#define CH_STRIDE       16384
#define NTOP            1024
#define TOPS_PER_WAVE   128       // 1024 / 8 waves
#define NBLK            256
#define NTHR            512
#define FEM_PER_BLK     180       // 46080 float4 pairs / 256 blocks

__global__ __launch_bounds__(NTHR) void meshloss_fused(
    const float* __restrict__ nm,
    const float* __restrict__ pc,
    const float* __restrict__ fem,
    float* __restrict__ ws)
{
    __shared__ float4 top[NTOP];        // 16 KB
    __shared__ float  pm[8 * 256];      // 8 KB: per-wave partial mins
    __shared__ float  wsum[8];

    const int t     = threadIdx.x;
    const int b     = blockIdx.x >> 6;      // batch
    const int chunk = blockIdx.x & 63;      // 256-point chunk
    const int w     = t >> 6;               // wave 0..7
    const int l     = t & 63;               // lane

    // ---- stage all 1024 tops (j==15 slice) with |t|^2 ----
    const float* nmb = nm + b * NM_BATCH_STRIDE;
    #pragma unroll
    for (int p0 = 0; p0 < NTOP; p0 += NTHR) {
        const int p = p0 + t;
        const int i = p >> 5, k = p & 31;
        const int base = i * 512 + 480 + k;          // (i*16+15)*32 + k
        float x = nmb[0 * CH_STRIDE + base];
        float y = nmb[1 * CH_STRIDE + base];
        float z = nmb[2 * CH_STRIDE + base];
        top[p] = make_float4(x, y, z, x * x + y * y + z * z);
    }

    // ---- load this lane's 4 points (same 4 points in every wave) ----
    const float* pcb = pc + b * NM_BATCH_STRIDE;
    const int m0 = chunk * 256 + l;                  // point p_j = l + j*64
    float px2[4], py2[4], pz2[4], pp[4], mn[4];
    #pragma unroll
    for (int j = 0; j < 4; ++j) {
        const int m = m0 + j * 64;
        float x = pcb[m];
        float y = pcb[CH_STRIDE + m];
        float z = pcb[2 * CH_STRIDE + m];
        pp[j]  = x * x + y * y + z * z;
        px2[j] = -2.0f * x;
        py2[j] = -2.0f * y;
        pz2[j] = -2.0f * z;
        mn[j]  = FLT_MAX;
    }
    __syncthreads();

    // ---- wave w scans its 128-top share for all 4 points/lane ----
    const float4* wtop = top + w * TOPS_PER_WAVE;
    #pragma unroll 2
    for (int g = 0; g < TOPS_PER_WAVE / 8; ++g) {
        float4 T0 = wtop[g * 8 + 0];
        float4 T1 = wtop[g * 8 + 1];
        float4 T2 = wtop[g * 8 + 2];
        float4 T3 = wtop[g * 8 + 3];
        float4 T4 = wtop[g * 8 + 4];
        float4 T5 = wtop[g * 8 + 5];
        float4 T6 = wtop[g * 8 + 6];
        float4 T7 = wtop[g * 8 + 7];
        #pragma unroll
        for (int j = 0; j < 4; ++j) {
            #define DISTD(T) __builtin_fmaf(px2[j], T.x, \
                             __builtin_fmaf(py2[j], T.y, \
                             __builtin_fmaf(pz2[j], T.z, T.w)))
            float d0 = DISTD(T0);
            float d1 = DISTD(T1);
            float d2 = DISTD(T2);
            float d3 = DISTD(T3);
            float d4 = DISTD(T4);
            float d5 = DISTD(T5);
            float d6 = DISTD(T6);
            float d7 = DISTD(T7);
            #undef DISTD
            mn[j] = fminf(mn[j], fminf(d0, d1));   // v_min3_f32
            mn[j] = fminf(mn[j], fminf(d2, d3));
            mn[j] = fminf(mn[j], fminf(d4, d5));
            mn[j] = fminf(mn[j], fminf(d6, d7));
        }
    }

    // ---- per-wave partial (+|p|^2, commutes with cross-wave min) ----
    #pragma unroll
    for (int j = 0; j < 4; ++j)
        pm[w * 256 + l + j * 64] = mn[j] + pp[j];
    __syncthreads();

    // ---- 8-way min combine (threads 0..255, conflict-free stride-1KB reads) ----
    float v = 0.0f;
    if (t < 256) {
        float d = pm[t];
        #pragma unroll
        for (int ww = 1; ww < 8; ++ww)
            d = fminf(d, pm[ww * 256 + t]);
        v = d * (1.0f / 65536.0f);
    }

    // ---- fem MSE slice: 180 float4 pairs per block ----
    if (t < FEM_PER_BLK) {
        const int q   = blockIdx.x * FEM_PER_BLK + t;   // < 46080
        const int bci = q / 120;
        const int r   = q - bci * 120;
        const int s   = bci * 128 + r;
        float4 a = reinterpret_cast<const float4*>(nm)[s];
        float4 f = reinterpret_cast<const float4*>(fem)[s];
        float dx = a.x - f.x, dy = a.y - f.y, dz = a.z - f.z, dw = a.w - f.w;
        v += (dx * dx + dy * dy + dz * dz + dw * dw) * (1.0f / 184320.0f);
    }

    // ---- block reduce (8 waves) + plain store ----
    for (int o = 32; o > 0; o >>= 1) v += __shfl_down(v, o, 64);
    if (l == 0) wsum[w] = v;
    __syncthreads();
    if (t == 0) {
        float s = 0.0f;
        #pragma unroll
        for (int ww = 0; ww < 8; ++ww) s += wsum[ww];
        ws[blockIdx.x] = s;
    }
}

__global__ __launch_bounds__(256) void meshloss_final(
    const float* __restrict__ ws, float* __restrict__ out)
{
    __shared__ float s4[4];
    const int t = threadIdx.x;
    float v = ws[t];
    for (int o = 32; o > 0; o >>= 1) v += __shfl_down(v, o, 64);
    if ((t & 63) == 0) s4[t >> 6] = v;
    __syncthreads();
    if (t == 0) out[0] = s4[0] + s4[1] + s4[2] + s4[3];
}

extern "C" void kernel_launch(void* const* d_in, const int* in_sizes, int n_in,
                              void* d_out, int out_size, void* d_ws, size_t ws_size,
                              hipStream_t stream) {
    const float* nm  = (const float*)d_in[0];
    const float* pc  = (const float*)d_in[1];
    const float* fem = (const float*)d_in[2];
    float* out = (float*)d_out;
    float* ws  = (float*)d_ws;

    meshloss_fused<<<NBLK, NTHR, 0, stream>>>(nm, pc, fem, ws);
    meshloss_final<<<1, 256, 0, stream>>>(ws, out);
}